// Round 1
// baseline (299.066 us; speedup 1.0000x reference)
//
#include <hip/hip_runtime.h>
#include <hip/hip_bf16.h>
#include <cstdint>

#define BATCH 4096
#define INF   1024
#define OUTF  1024
#define LCH   12              // 11 spline channels + 1 base channel
#define KTOT  (INF*LCH)       // 12288

#define BM 128
#define BN 128
#define IC 8                  // input features per chunk
#define BK (IC*LCH)           // 96
#define NCHUNK (INF/IC)       // 128
#define LDA 104               // padded A row (ushorts); 208 B = 13*16, conflict-free

typedef __bf16 bf16x8 __attribute__((ext_vector_type(8)));
typedef float  f32x4  __attribute__((ext_vector_type(4)));

__device__ __forceinline__ unsigned short f2bf(float f) {
  // round-to-nearest-even bf16
  unsigned int u = __builtin_bit_cast(unsigned int, f);
  u += 0x7FFFu + ((u >> 16) & 1u);
  return (unsigned short)(u >> 16);
}

__device__ __forceinline__ void async_copy16(const void* g, void* l) {
  __builtin_amdgcn_global_load_lds(
      (const __attribute__((address_space(1))) unsigned int*)g,
      (__attribute__((address_space(3))) unsigned int*)l,
      16, 0, 0);
}

// ---------------- kernel 1: weights f32 -> bf16, k = i*12 + l ----------------
__global__ __launch_bounds__(256) void kan_build_wt(
    const float* __restrict__ sw,        // [OUTF][INF][11]
    const float* __restrict__ bw,        // [OUTF][INF]
    unsigned short* __restrict__ Wt)     // [OUTF][KTOT] bf16
{
  int idx = blockIdx.x * 256 + threadIdx.x;     // 0 .. 1024*1024-1
  int o = idx >> 10;
  int i = idx & 1023;
  const float* s = sw + (size_t)(o * 1024 + i) * 11;
  unsigned short v[12];
#pragma unroll
  for (int l = 0; l < 11; ++l) v[l] = f2bf(s[l]);
  v[11] = f2bf(bw[o * 1024 + i]);
  unsigned short* d = Wt + (size_t)o * KTOT + i * 12;   // 8B aligned
  *reinterpret_cast<ushort4*>(d + 0) = make_ushort4(v[0], v[1], v[2],  v[3]);
  *reinterpret_cast<ushort4*>(d + 4) = make_ushort4(v[4], v[5], v[6],  v[7]);
  *reinterpret_cast<ushort4*>(d + 8) = make_ushort4(v[8], v[9], v[10], v[11]);
}

// ---------------- kernel 2: fused basis-build + MFMA GEMM ----------------
__global__ __launch_bounds__(256, 1) void kan_gemm(
    const float* __restrict__ x,             // [BATCH][INF]
    const unsigned short* __restrict__ Wt,   // [OUTF][KTOT] bf16
    float* __restrict__ out)                 // [BATCH][OUTF]
{
  __shared__ unsigned short Asm[BM * LDA];             // 26624 B
  __shared__ unsigned short Bsm[(BK / 8) * BN * 8];    // 12*128*8 us = 24576 B

  const int tid  = threadIdx.x;
  const int lane = tid & 63;
  const int wid  = tid >> 6;              // 0..3
  const int wm   = (wid >> 1) * 64;       // wave row offset
  const int wn   = (wid & 1) * 64;        // wave col offset
  const int bm   = (int)blockIdx.x >> 3;  // 0..31
  const int bn   = (int)blockIdx.x & 7;   // 0..7
  const int lr   = lane & 15;             // fragment row/col
  const int lk   = lane >> 4;             // k-group 0..3

  // A-build mapping: thread -> (row ab, 4 consecutive i at offset ah)
  const int ab = tid >> 1;                // 0..127
  const int ah = (tid & 1) * 4;           // 0 or 4
  const float* xrow = x + (size_t)(bm * BM + ab) * INF;

  f32x4 acc[4][4] = {};

  for (int c = 0; c < NCHUNK; ++c) {
    const int i0 = c * IC;
    const int k0 = c * BK;

    // ---- stage B tile (async global->LDS), [kk][o][8] granules ----
#pragma unroll
    for (int q = 0; q < 6; ++q) {
      int g  = (wid * 6 + q) * 64 + lane;   // granule id 0..1535
      int kk = g >> 7;                      // 0..11
      int oo = g & 127;
      const unsigned short* src = Wt + (size_t)(bn * BN + oo) * KTOT + (k0 + kk * 8);
      unsigned short* dst = &Bsm[(wid * 6 + q) * 512];  // wave-uniform base
      async_copy16(src, dst);
    }

    // ---- build A tile (basis) ----
    {
      float4 xv = *reinterpret_cast<const float4*>(xrow + i0 + ah);
#pragma unroll
      for (int j = 0; j < 4; ++j) {
        float xx = (j == 0) ? xv.x : (j == 1) ? xv.y : (j == 2) ? xv.z : xv.w;
        float u  = fmaf(xx, 4.0f, 7.0f);       // (x+1.75)/0.25
        float fm = floorf(u);
        int   mi = (int)fm;
        mi = mi < 3 ? 3 : (mi > 10 ? 10 : mi);
        float t  = u - (float)mi;
        float s  = 1.0f - t;
        float t2 = t * t, t3 = t2 * t;
        float w0 = (s * s * s) * (1.0f / 6.0f);          // B_{m-3}
        float w3 = t3 * (1.0f / 6.0f);                   // B_{m}
        float w1 = fmaf(0.5f, t3, 2.0f / 3.0f) - t2;     // B_{m-2}
        float w2 = 1.0f - w0 - w1 - w3;                  // B_{m-1}
        int ls = mi - 3;                                 // 0..7

        // pack 4 weights and place at bit offset 16*ls within 192-bit row
        unsigned long long W64 =
            (unsigned long long)f2bf(w0)
          | ((unsigned long long)f2bf(w1) << 16)
          | ((unsigned long long)f2bf(w2) << 32)
          | ((unsigned long long)f2bf(w3) << 48);
        int sh  = ls << 4;                // 0..112
        int a   = sh & 63;
        unsigned long long lo = W64 << a;
        unsigned long long hi = a ? (W64 >> (64 - a)) : 0ull;
        unsigned long long word0 = (sh < 64) ? lo : 0ull;
        unsigned long long word1 = (sh < 64) ? hi : lo;
        unsigned long long word2 = (sh < 64) ? 0ull : hi;
        word2 |= ((unsigned long long)f2bf(xx)) << 48;   // slot 11 = x (base chan)

        unsigned long long* p64 =
            reinterpret_cast<unsigned long long*>(&Asm[ab * LDA + (ah + j) * 12]);
        p64[0] = word0;
        p64[1] = word1;
        p64[2] = word2;
      }
    }

    __syncthreads();   // A visible to all waves; B async loads drained

    // ---- MFMA: 3 k-steps of 32 ----
#pragma unroll
    for (int kk32 = 0; kk32 < 3; ++kk32) {
      bf16x8 af[4], bfr[4];
#pragma unroll
      for (int mf = 0; mf < 4; ++mf)
        af[mf] = *reinterpret_cast<const bf16x8*>(
            &Asm[(wm + mf * 16 + lr) * LDA + kk32 * 32 + lk * 8]);
#pragma unroll
      for (int nf = 0; nf < 4; ++nf)
        bfr[nf] = *reinterpret_cast<const bf16x8*>(
            &Bsm[(((kk32 * 4 + lk) * 128) + (wn + nf * 16 + lr)) * 8]);
#pragma unroll
      for (int mf = 0; mf < 4; ++mf)
#pragma unroll
        for (int nf = 0; nf < 4; ++nf)
          acc[mf][nf] = __builtin_amdgcn_mfma_f32_16x16x32_bf16(
              af[mf], bfr[nf], acc[mf][nf], 0, 0, 0);
    }

    __syncthreads();   // reads done before next chunk overwrites LDS
  }

  // ---- epilogue: D row = (lane>>4)*4 + v, col = lane&15 ----
#pragma unroll
  for (int mf = 0; mf < 4; ++mf) {
#pragma unroll
    for (int v = 0; v < 4; ++v) {
      int row = bm * BM + wm + mf * 16 + lk * 4 + v;
      float* orow = out + (size_t)row * OUTF + bn * BN + wn + lr;
#pragma unroll
      for (int nf = 0; nf < 4; ++nf)
        orow[nf * 16] = acc[mf][nf][v];
    }
  }
}

extern "C" void kernel_launch(void* const* d_in, const int* in_sizes, int n_in,
                              void* d_out, int out_size, void* d_ws, size_t ws_size,
                              hipStream_t stream) {
  const float* x  = (const float*)d_in[0];   // [4096][1024]
  const float* bw = (const float*)d_in[1];   // [1024][1024]
  const float* sw = (const float*)d_in[2];   // [1024][1024][11]
  float* out = (float*)d_out;

  unsigned short* Wt = (unsigned short*)d_ws;
  if (ws_size < (size_t)OUTF * KTOT * sizeof(unsigned short)) return;  // need 25.2 MB

  kan_build_wt<<<(OUTF * INF) / 256, 256, 0, stream>>>(sw, bw, Wt);
  kan_gemm<<<(BATCH / BM) * (OUTF / BN), 256, 0, stream>>>(x, Wt, out);
}

// Round 2
// 190.585 us; speedup vs baseline: 1.5692x; 1.5692x over previous
//
#include <hip/hip_runtime.h>
#include <hip/hip_bf16.h>
#include <cstdint>

#define BATCH 4096
#define INF   1024
#define OUTF  1024
#define LCH   12              // 11 spline channels + 1 base channel
#define KTOT  (INF*LCH)       // 12288

#define BM 128
#define BN 128
#define IC 8                  // input features per chunk
#define BK (IC*LCH)           // 96
#define NCHUNK (INF/IC)       // 128
#define LDA 104               // padded A row (ushorts); 208 B = 13*16
#define THREADS 512

typedef __bf16 bf16x8 __attribute__((ext_vector_type(8)));
typedef float  f32x4  __attribute__((ext_vector_type(4)));

__device__ __forceinline__ unsigned short f2bf(float f) {
  unsigned int u = __builtin_bit_cast(unsigned int, f);
  u += 0x7FFFu + ((u >> 16) & 1u);
  return (unsigned short)(u >> 16);
}

__device__ __forceinline__ void async_copy16(const void* g, void* l) {
  __builtin_amdgcn_global_load_lds(
      (const __attribute__((address_space(1))) unsigned int*)g,
      (__attribute__((address_space(3))) unsigned int*)l,
      16, 0, 0);
}

// ---------------- kernel 1: weights f32 -> bf16, k = i*12 + l ----------------
__global__ __launch_bounds__(256) void kan_build_wt(
    const float* __restrict__ sw,        // [OUTF][INF][11]
    const float* __restrict__ bw,        // [OUTF][INF]
    unsigned short* __restrict__ Wt)     // [OUTF][KTOT] bf16
{
  int idx = blockIdx.x * 256 + threadIdx.x;
  int o = idx >> 10;
  int i = idx & 1023;
  const float* s = sw + (size_t)(o * 1024 + i) * 11;
  unsigned short v[12];
#pragma unroll
  for (int l = 0; l < 11; ++l) v[l] = f2bf(s[l]);
  v[11] = f2bf(bw[o * 1024 + i]);
  unsigned short* d = Wt + (size_t)o * KTOT + i * 12;
  *reinterpret_cast<ushort4*>(d + 0) = make_ushort4(v[0], v[1], v[2],  v[3]);
  *reinterpret_cast<ushort4*>(d + 4) = make_ushort4(v[4], v[5], v[6],  v[7]);
  *reinterpret_cast<ushort4*>(d + 8) = make_ushort4(v[8], v[9], v[10], v[11]);
}

// ---------------- kernel 2: fused basis-build + MFMA GEMM ----------------
__global__ __launch_bounds__(THREADS, 1) void kan_gemm(
    const float* __restrict__ x,             // [BATCH][INF]
    const unsigned short* __restrict__ Wt,   // [OUTF][KTOT] bf16
    float* __restrict__ out)                 // [BATCH][OUTF]
{
  __shared__ unsigned short Abuf[2][BM * LDA];          // 2 x 26624 B
  __shared__ unsigned short Bbuf[2][(BK / 8) * BN * 8]; // 2 x 24576 B

  const int tid  = threadIdx.x;
  const int lane = tid & 63;
  const int wid  = tid >> 6;              // 0..7
  const int wm   = (wid >> 1) * 32;       // 4 wave-rows of 32
  const int wn   = (wid & 1) * 64;        // 2 wave-cols of 64
  const int bm   = (int)blockIdx.x >> 3;  // 0..31
  const int bn   = (int)blockIdx.x & 7;   // 0..7
  const int lr   = lane & 15;
  const int lk   = lane >> 4;

  // A-build mapping: thread -> (row ab, 2 consecutive i at offset ai0)
  const int ab  = tid >> 2;               // 0..127
  const int ai0 = (tid & 3) * 2;          // 0,2,4,6
  const float* xrow = x + (size_t)(bm * BM + ab) * INF + ai0;

  unsigned short* Ac = Abuf[0]; unsigned short* An = Abuf[1];
  unsigned short* Bc = Bbuf[0]; unsigned short* Bn = Bbuf[1];

  f32x4 acc[2][4] = {};

  // ---- helpers ----
  auto stageB = [&](int c, unsigned short* Bd) {
#pragma unroll
    for (int q = 0; q < 3; ++q) {
      int g  = (wid * 3 + q) * 64 + lane;   // granule 0..1535
      int kk = g >> 7;                      // 0..11
      int oo = g & 127;
      const unsigned short* src = Wt + (size_t)(bn * BN + oo) * KTOT + (c * BK + kk * 8);
      async_copy16(src, Bd + (wid * 3 + q) * 512);   // wave-uniform base
    }
  };

  auto buildA = [&](float2 xv, unsigned short* Ad) {
#pragma unroll
    for (int j = 0; j < 2; ++j) {
      float xx = (j == 0) ? xv.x : xv.y;
      float u  = fmaf(xx, 4.0f, 7.0f);       // in (3,11)
      float fm = floorf(u);
      int   mi = (int)fm;                    // 3..10
      float t  = u - fm;
      float s  = 1.0f - t;
      float t2 = t * t, t3 = t2 * t;
      float w0 = (s * s * s) * (1.0f / 6.0f);
      float w3 = t3 * (1.0f / 6.0f);
      float w1 = fmaf(0.5f, t3, 2.0f / 3.0f) - t2;
      float w2 = 1.0f - w0 - w1 - w3;
      int ls = mi - 3;                       // 0..7

      unsigned long long W64 =
          (unsigned long long)f2bf(w0)
        | ((unsigned long long)f2bf(w1) << 16)
        | ((unsigned long long)f2bf(w2) << 32)
        | ((unsigned long long)f2bf(w3) << 48);
      int sh = ls << 4;                      // 0..112
      int a  = sh & 63;
      unsigned long long lo = W64 << a;
      unsigned long long hi = a ? (W64 >> (64 - a)) : 0ull;
      unsigned long long word0 = (sh < 64) ? lo : 0ull;
      unsigned long long word1 = (sh < 64) ? hi : lo;
      unsigned long long word2 = (sh < 64) ? 0ull : hi;
      word2 |= ((unsigned long long)f2bf(xx)) << 48;   // slot 11 = x (base chan)

      unsigned long long* p64 =
          reinterpret_cast<unsigned long long*>(&Ad[ab * LDA + (ai0 + j) * 12]);
      p64[0] = word0;
      p64[1] = word1;
      p64[2] = word2;
    }
  };

  // ---- prologue: fill buffers for c=0, prefetch x for c=1 ----
  float2 xcur = *reinterpret_cast<const float2*>(xrow);
  stageB(0, Bc);
  buildA(xcur, Ac);
  float2 xnxt = *reinterpret_cast<const float2*>(xrow + IC);
  __syncthreads();

  for (int c = 0; c < NCHUNK; ++c) {
    // stage next chunk into the ^1 buffers (covered by this iter's MFMA)
    if (c + 1 < NCHUNK) {
      stageB(c + 1, Bn);
      buildA(xnxt, An);
      if (c + 2 < NCHUNK)
        xnxt = *reinterpret_cast<const float2*>(xrow + (c + 2) * IC);
    }

    // ---- MFMA on current buffers ----
#pragma unroll
    for (int kk32 = 0; kk32 < 3; ++kk32) {
      bf16x8 af[2], bfr[4];
#pragma unroll
      for (int mf = 0; mf < 2; ++mf)
        af[mf] = *reinterpret_cast<const bf16x8*>(
            &Ac[(wm + mf * 16 + lr) * LDA + kk32 * 32 + lk * 8]);
#pragma unroll
      for (int nf = 0; nf < 4; ++nf)
        bfr[nf] = *reinterpret_cast<const bf16x8*>(
            &Bc[(((kk32 * 4 + lk) * 128) + (wn + nf * 16 + lr)) * 8]);
#pragma unroll
      for (int mf = 0; mf < 2; ++mf)
#pragma unroll
        for (int nf = 0; nf < 4; ++nf)
          acc[mf][nf] = __builtin_amdgcn_mfma_f32_16x16x32_bf16(
              af[mf], bfr[nf], acc[mf][nf], 0, 0, 0);
    }

    __syncthreads();   // next buffers ready; current reads done

    // swap buffers
    unsigned short* t;
    t = Ac; Ac = An; An = t;
    t = Bc; Bc = Bn; Bn = t;
  }

  // ---- epilogue ----
#pragma unroll
  for (int mf = 0; mf < 2; ++mf) {
#pragma unroll
    for (int v = 0; v < 4; ++v) {
      int row = bm * BM + wm + mf * 16 + lk * 4 + v;
      float* orow = out + (size_t)row * OUTF + bn * BN + wn + lr;
#pragma unroll
      for (int nf = 0; nf < 4; ++nf)
        orow[nf * 16] = acc[mf][nf][v];
    }
  }
}

extern "C" void kernel_launch(void* const* d_in, const int* in_sizes, int n_in,
                              void* d_out, int out_size, void* d_ws, size_t ws_size,
                              hipStream_t stream) {
  const float* x  = (const float*)d_in[0];   // [4096][1024]
  const float* bw = (const float*)d_in[1];   // [1024][1024]
  const float* sw = (const float*)d_in[2];   // [1024][1024][11]
  float* out = (float*)d_out;

  unsigned short* Wt = (unsigned short*)d_ws;
  if (ws_size < (size_t)OUTF * KTOT * sizeof(unsigned short)) return;

  kan_build_wt<<<(OUTF * INF) / 256, 256, 0, stream>>>(sw, bw, Wt);
  kan_gemm<<<(BATCH / BM) * (OUTF / BN), THREADS, 0, stream>>>(x, Wt, out);
}

// Round 3
// 165.996 us; speedup vs baseline: 1.8017x; 1.1481x over previous
//
#include <hip/hip_runtime.h>
#include <hip/hip_bf16.h>
#include <cstdint>

#define BATCH 4096
#define INF   1024
#define OUTF  1024
#define LCH   12              // 11 spline channels + 1 base channel
#define KTOT  (INF*LCH)       // 12288

#define BM 128
#define BN 128
#define IC 8                  // input features per chunk
#define BK (IC*LCH)           // 96
#define NCHUNK (INF/IC)       // 128
#define LDA 96                // unpadded; 12 granules/row is bank-balanced here
#define THREADS 512

typedef __bf16 bf16x8 __attribute__((ext_vector_type(8)));
typedef float  f32x4  __attribute__((ext_vector_type(4)));
typedef unsigned long long ull;

struct alignas(16) U2 { ull x, y; };

__device__ __forceinline__ unsigned short f2bf(float f) {
  unsigned int u = __builtin_bit_cast(unsigned int, f);
  u += 0x7FFFu + ((u >> 16) & 1u);
  return (unsigned short)(u >> 16);
}

__device__ __forceinline__ void async_copy16(const void* g, void* l) {
  __builtin_amdgcn_global_load_lds(
      (const __attribute__((address_space(1))) unsigned int*)g,
      (__attribute__((address_space(3))) unsigned int*)l,
      16, 0, 0);
}

// pipeline barrier: keep the newest 4 VMEM ops (this iter's x-load + 3 B-DMAs)
// in flight; drain everything older + all LDS ops, then block barrier.
#define PIPE_BARRIER() do {                                        \
  asm volatile("s_waitcnt vmcnt(4) lgkmcnt(0)" ::: "memory");      \
  __builtin_amdgcn_sched_barrier(0);                               \
  __builtin_amdgcn_s_barrier();                                    \
  __builtin_amdgcn_sched_barrier(0);                               \
} while (0)

// ---------------- kernel 1: weights f32 -> bf16, k = i*12 + l ----------------
__global__ __launch_bounds__(256) void kan_build_wt(
    const float* __restrict__ sw,        // [OUTF][INF][11]
    const float* __restrict__ bw,        // [OUTF][INF]
    unsigned short* __restrict__ Wt)     // [OUTF][KTOT] bf16
{
  int idx = blockIdx.x * 256 + threadIdx.x;
  int o = idx >> 10;
  int i = idx & 1023;
  const float* s = sw + (size_t)(o * 1024 + i) * 11;
  unsigned short v[12];
#pragma unroll
  for (int l = 0; l < 11; ++l) v[l] = f2bf(s[l]);
  v[11] = f2bf(bw[o * 1024 + i]);
  unsigned short* d = Wt + (size_t)o * KTOT + i * 12;
  *reinterpret_cast<ushort4*>(d + 0) = make_ushort4(v[0], v[1], v[2],  v[3]);
  *reinterpret_cast<ushort4*>(d + 4) = make_ushort4(v[4], v[5], v[6],  v[7]);
  *reinterpret_cast<ushort4*>(d + 8) = make_ushort4(v[8], v[9], v[10], v[11]);
}

// ---------------- kernel 2: fused basis-build + MFMA GEMM ----------------
__global__ __launch_bounds__(THREADS, 1) void kan_gemm(
    const float* __restrict__ x,             // [BATCH][INF]
    const unsigned short* __restrict__ Wt,   // [OUTF][KTOT] bf16
    float* __restrict__ out)                 // [BATCH][OUTF]
{
  __shared__ unsigned short Abuf[2][BM * LDA];          // 2 x 24576 B
  __shared__ unsigned short Bbuf[3][(BK / 8) * BN * 8]; // 3 x 24576 B  -> 120 KB

  const int tid  = threadIdx.x;
  const int lane = tid & 63;
  const int wid  = tid >> 6;              // 0..7
  const int wm   = (wid >> 1) * 32;       // 4 wave-rows of 32
  const int wn   = (wid & 1) * 64;        // 2 wave-cols of 64
  const int bm   = (int)blockIdx.x >> 3;  // 0..31
  const int bn   = (int)blockIdx.x & 7;   // 0..7
  const int lr   = lane & 15;
  const int lk   = lane >> 4;

  // A-build mapping: thread -> (row ab, 2 consecutive i at offset ai0)
  const int ab  = tid >> 2;               // 0..127
  const int ai0 = (tid & 3) * 2;          // 0,2,4,6
  const float* xrow = x + (size_t)(bm * BM + ab) * INF + ai0;

  unsigned short* Acur = Abuf[0]; unsigned short* Aalt = Abuf[1];
  unsigned short* Bcur = Bbuf[0]; unsigned short* Bnxt = Bbuf[1];
  unsigned short* Bnn  = Bbuf[2];

  f32x4 acc[2][4] = {};

  auto stageB = [&](int c, unsigned short* Bd) {
#pragma unroll
    for (int q = 0; q < 3; ++q) {
      int g  = (wid * 3 + q) * 64 + lane;   // dest granule 0..1535 (linear, DMA rule)
      int kk = g >> 7;                      // 0..11
      int oo = g & 127;
      const unsigned short* src = Wt + (size_t)(bn * BN + oo) * KTOT + (c * BK + kk * 8);
      async_copy16(src, Bd + (wid * 3 + q) * 512);   // wave-uniform base
    }
  };

  auto buildA = [&](float2 xv, unsigned short* Ad) {
    ull W[6];
#pragma unroll
    for (int j = 0; j < 2; ++j) {
      float xx = (j == 0) ? xv.x : xv.y;
      float u  = fmaf(xx, 4.0f, 7.0f);       // in (3,11); x in (-1,1)
      float fm = floorf(u);
      int   mi = (int)fm;                    // 3..10
      float t  = u - fm;
      float s  = 1.0f - t;
      float t2 = t * t, t3 = t2 * t;
      float w0 = (s * s * s) * (1.0f / 6.0f);
      float w3 = t3 * (1.0f / 6.0f);
      float w1 = fmaf(0.5f, t3, 2.0f / 3.0f) - t2;
      float w2 = 1.0f - w0 - w1 - w3;
      int ls = mi - 3;                       // 0..7

      ull W64 = (ull)f2bf(w0)
              | ((ull)f2bf(w1) << 16)
              | ((ull)f2bf(w2) << 32)
              | ((ull)f2bf(w3) << 48);
      int sh = ls << 4;                      // 0..112
      int a  = sh & 63;
      ull lo = W64 << a;
      ull hi = a ? (W64 >> (64 - a)) : 0ull;
      W[3 * j + 0] = (sh < 64) ? lo : 0ull;
      W[3 * j + 1] = (sh < 64) ? hi : lo;
      W[3 * j + 2] = ((sh < 64) ? 0ull : hi) | ((ull)f2bf(xx) << 48); // slot 11 = x
    }
    // 24 contiguous ushorts = 3x ds_write_b128, 16B-aligned, bank-balanced
    U2* p = reinterpret_cast<U2*>(&Ad[ab * LDA + ai0 * 12]);
    U2 u0; u0.x = W[0]; u0.y = W[1];
    U2 u1; u1.x = W[2]; u1.y = W[3];
    U2 u2; u2.x = W[4]; u2.y = W[5];
    p[0] = u0; p[1] = u1; p[2] = u2;
  };

  // ---- prologue ----
  float2 x0 = *reinterpret_cast<const float2*>(xrow);          // chunk 0
  stageB(0, Bcur);
  buildA(x0, Acur);
  float2 xa = *reinterpret_cast<const float2*>(xrow + IC);     // chunk 1
  stageB(1, Bnxt);
  PIPE_BARRIER();   // drains B0 + A0 writes; keeps {x1, B1 dma} in flight

  for (int c = 0; c < NCHUNK; ++c) {
    // issue order matters for the vmcnt(4) count: x-load first, then 3 DMAs
    int cf = (c + 2 < NCHUNK) ? (c + 2) : (NCHUNK - 1);        // clamped
    float2 xb = *reinterpret_cast<const float2*>(xrow + cf * IC);
    stageB(cf, Bnn);
    buildA(xa, Aalt);          // chunk c+1 basis (xa loaded one iter ago)

    // ---- MFMA on current buffers ----
#pragma unroll
    for (int kk32 = 0; kk32 < 3; ++kk32) {
      bf16x8 af[2], bfr[4];
#pragma unroll
      for (int mf = 0; mf < 2; ++mf)
        af[mf] = *reinterpret_cast<const bf16x8*>(
            &Acur[(wm + mf * 16 + lr) * LDA + kk32 * 32 + lk * 8]);
#pragma unroll
      for (int nf = 0; nf < 4; ++nf)
        bfr[nf] = *reinterpret_cast<const bf16x8*>(
            &Bcur[(((kk32 * 4 + lk) * 128) + (wn + nf * 16 + lr)) * 8]);
#pragma unroll
      for (int mf = 0; mf < 2; ++mf)
#pragma unroll
        for (int nf = 0; nf < 4; ++nf)
          acc[mf][nf] = __builtin_amdgcn_mfma_f32_16x16x32_bf16(
              af[mf], bfr[nf], acc[mf][nf], 0, 0, 0);
    }

    PIPE_BARRIER();   // everyone's A[c+1] writes + B[c+1] DMA done; B[c+2]/x in flight

    // rotate buffers
    unsigned short* t = Bcur; Bcur = Bnxt; Bnxt = Bnn; Bnn = t;
    t = Acur; Acur = Aalt; Aalt = t;
    xa = xb;
  }

  // ---- epilogue ----
#pragma unroll
  for (int mf = 0; mf < 2; ++mf) {
#pragma unroll
    for (int v = 0; v < 4; ++v) {
      int row = bm * BM + wm + mf * 16 + lk * 4 + v;
      float* orow = out + (size_t)row * OUTF + bn * BN + wn + lr;
#pragma unroll
      for (int nf = 0; nf < 4; ++nf)
        orow[nf * 16] = acc[mf][nf][v];
    }
  }
}

extern "C" void kernel_launch(void* const* d_in, const int* in_sizes, int n_in,
                              void* d_out, int out_size, void* d_ws, size_t ws_size,
                              hipStream_t stream) {
  const float* x  = (const float*)d_in[0];   // [4096][1024]
  const float* bw = (const float*)d_in[1];   // [1024][1024]
  const float* sw = (const float*)d_in[2];   // [1024][1024][11]
  float* out = (float*)d_out;

  unsigned short* Wt = (unsigned short*)d_ws;
  if (ws_size < (size_t)OUTF * KTOT * sizeof(unsigned short)) return;

  kan_build_wt<<<(OUTF * INF) / 256, 256, 0, stream>>>(sw, bw, Wt);
  kan_gemm<<<(BATCH / BM) * (OUTF / BN), THREADS, 0, stream>>>(x, Wt, out);
}